// Round 5
// baseline (582.903 us; speedup 1.0000x reference)
//
#include <hip/hip_runtime.h>

// CavityModel forward: gaussian blur -> 3x(conv3d+maxpool+BN(batch stats)+leaky)
// -> dense 64->128 (+BN+leaky) -> 128->100 (+leaky) -> 100->20.
// R5: conv1 with 2x2x2-pool register blocking (fix LDS-BW bound), type-split splat,
// single-pass conv2. Fields + conv1 weights staged as bf16 (empirically free).

#define G2 324
#define G3 5832
#define NT 6
#define BATCH 256
#define APE 100
#define EPS 1e-5f

typedef unsigned short u16;
typedef unsigned int u32;

__device__ __forceinline__ float leaky(float x) { return x >= 0.0f ? x : 0.01f * x; }
__device__ __forceinline__ u16 f2b(float f) {
    union { float f; u32 u; } v; v.f = f;
    return (u16)((v.u + 0x7FFFu + ((v.u >> 16) & 1u)) >> 16);
}
__device__ __forceinline__ float b2f(u16 u) {
    union { u32 u; float f; } v; v.u = ((u32)u) << 16; return v.f;
}

// ---------- K1a: gaussian splat, type-split: block = (env, type-triple h)
// field half [3][18^3] in LDS (70 KB) -> 2 blocks/CU; output bf16 pairs.
__global__ __launch_bounds__(512) void k_splat(const float* __restrict__ pos,
        const int* __restrict__ types, u32* __restrict__ fields) {
    __shared__ float fld[3 * G3];    // 69984 B
    __shared__ float ew[64 * 27];
    __shared__ short i0a[64 * 3];
    __shared__ int al[64];
    __shared__ int cnt;
    const int bx = blockIdx.x, b = bx & 255, h = bx >> 8, tid = threadIdx.x;

    float4* f4 = (float4*)fld;
    for (int i = tid; i < 3 * G3 / 4; i += 512) f4[i] = make_float4(0, 0, 0, 0);
    if (tid == 0) cnt = 0;
    __syncthreads();
    if (tid < APE) {
        const int t = types[b * APE + tid];
        if (t >= 3 * h && t < 3 * h + 3) {
            const int j = atomicAdd(&cnt, 1);
            if (j < 64) al[j] = tid | ((t - 3 * h) << 16);
        }
    }
    __syncthreads();
    const int NA = min(cnt, 64);
    if (tid < 3 * NA) {
        const int la = tid / 3, ax = tid % 3;
        const int n = b * APE + (al[la] & 0xffff);
        const float p = pos[n * 3 + ax];
        int i0 = (int)ceilf(p + 4.0f);
        i0 = max(0, min(9, i0));
        i0a[la * 3 + ax] = (short)i0;
        float e[18], s = 0.0f;
        #pragma unroll
        for (int g = 0; g < 18; ++g) {
            float d = (float)g - 8.5f - p;
            e[g] = __expf(d * d * (-1.0f / 0.72f));
            s += e[g];
        }
        const float inv = 1.0f / s;
        #pragma unroll
        for (int q = 0; q < 9; ++q) ew[la * 27 + ax * 9 + q] = e[i0 + q] * inv;
    }
    __syncthreads();
    for (int idx = tid; idx < NA * 729; idx += 512) {
        const int la = idx / 729, r = idx % 729;
        const int di = r / 81, dj = (r / 9) % 9, dk = r % 9;
        const int a = al[la];
        atomicAdd(&fld[(a >> 16) * G3 + (i0a[la * 3] + di) * G2
                       + (i0a[la * 3 + 1] + dj) * 18 + (i0a[la * 3 + 2] + dk)],
                  ew[la * 27 + di] * ew[la * 27 + 9 + dj] * ew[la * 27 + 18 + dk]);
    }
    __syncthreads();
    u32* dst = fields + ((size_t)b * 6 + 3 * h) * (G3 / 2);
    for (int i = tid; i < 3 * G3 / 2; i += 512)
        dst[i] = (u32)f2b(fld[2 * i]) | ((u32)f2b(fld[2 * i + 1]) << 16);
}

// ---------- K1b: conv1 (6->16, pad1) + 2x2x2 maxpool + bias + bn1 stats
// block = (env, Xg 0..2, Zg 0..2); thread = (c2 8, Xl 3, Y 9) = 216 active / 256.
// Each thread: acc[2ch][2ox][2oy][6oz] -> pool fully in-register.
template <int ZG>
__device__ __forceinline__ void conv1_body(int b, int Xg, int tid,
        float* fldT, const u32* wsp, const float* bs,
        float* s_sum, float* s_ssq,
        const u32* __restrict__ fields, float* __restrict__ a1,
        float* __restrict__ stO) {
    constexpr int ZBP = (ZG == 0) ? 0 : (ZG == 1) ? 2 : 5;   // first bf16-pair idx
    constexpr int NP  = (ZG == 1) ? 5 : 4;                   // pairs staged per row
    constexpr int ZL  = 2 * NP;                              // row length (floats)
    constexpr int ZOFF = (ZG == 0) ? -1 : 1;                 // zr = ozl + dz + ZOFF

    // stage 6ch x 8 x-planes x 18 y x NP z-pairs (x-halo zero-padded), stride 14
    const int PR = 18 * NP;
    for (int i = tid; i < 48 * PR; i += 256) {
        const int a = i / PR, rem = i % PR;      // a = ic*8 + ixl
        const int iy = rem / NP, p = rem % NP;
        const int ix = 6 * Xg - 1 + (a & 7);
        u32 v = 0;
        if (ix >= 0 && ix < 18)
            v = fields[(((size_t)(b * 6 + (a >> 3)) * 18 + ix) * 18 + iy) * 9 + ZBP + p];
        const int base = (a * 18 + iy) * 14 + 2 * p;
        fldT[base] = b2f((u16)v);
        fldT[base + 1] = b2f((u16)(v >> 16));
    }
    __syncthreads();

    if (tid < 216) {
        const int c2 = tid / 27, r = tid % 27, Xl = r / 9, Y = r % 9;
        float acc[2][2][2][6];
        #pragma unroll
        for (int c = 0; c < 2; ++c)
            #pragma unroll
            for (int o = 0; o < 2; ++o)
                #pragma unroll
                for (int p = 0; p < 2; ++p)
                    #pragma unroll
                    for (int z = 0; z < 6; ++z) acc[c][o][p][z] = 0.0f;

        for (int ic = 0; ic < 6; ++ic) {
            float wreg[2][27];
            #pragma unroll
            for (int d = 0; d < 27; ++d) {
                const u32 pw = wsp[(ic * 27 + d) * 8 + c2];
                wreg[0][d] = b2f((u16)pw);
                wreg[1][d] = b2f((u16)(pw >> 16));
            }
            #pragma unroll
            for (int lj = 0; lj < 4; ++lj) {
                const int iy = 2 * Y + lj - 1;
                const bool yok = (iy >= 0 && iy < 18);
                #pragma unroll
                for (int li = 0; li < 4; ++li) {
                    const int ixl = 2 * Xl + li;
                    float row[ZL];
                    if (yok) {
                        const float2* rp =
                            (const float2*)&fldT[(((ic << 3) + ixl) * 18 + iy) * 14];
                        #pragma unroll
                        for (int q = 0; q < NP; ++q) {
                            const float2 t2 = rp[q];
                            row[2 * q] = t2.x; row[2 * q + 1] = t2.y;
                        }
                    } else {
                        #pragma unroll
                        for (int z = 0; z < ZL; ++z) row[z] = 0.0f;
                    }
                    #pragma unroll
                    for (int o = 0; o < 2; ++o) {
                        const int dx = li - o;
                        if (dx < 0 || dx > 2) continue;
                        #pragma unroll
                        for (int p = 0; p < 2; ++p) {
                            const int dy = lj - p;
                            if (dy < 0 || dy > 2) continue;
                            const int wd = dx * 9 + dy * 3;
                            #pragma unroll
                            for (int dz = 0; dz < 3; ++dz) {
                                const float w0 = wreg[0][wd + dz];
                                const float w1 = wreg[1][wd + dz];
                                #pragma unroll
                                for (int oz = 0; oz < 6; ++oz) {
                                    const int zr = oz + dz + ZOFF;
                                    if (zr < 0 || zr >= ZL) continue;
                                    const float rv = row[zr];
                                    acc[0][o][p][oz] += w0 * rv;
                                    acc[1][o][p][oz] += w1 * rv;
                                }
                            }
                        }
                    }
                }
            }
        }
        // in-register 2x2x2 pool + bias + write + stats
        #pragma unroll
        for (int c = 0; c < 2; ++c) {
            const int ch = 2 * c2 + c;
            const float bb = bs[ch];
            float s0 = 0.0f, q0 = 0.0f;
            float* oP = &a1[(size_t)(b * 16 + ch) * 729
                            + (3 * Xg + Xl) * 81 + Y * 9 + 3 * ZG];
            #pragma unroll
            for (int Zp = 0; Zp < 3; ++Zp) {
                float m = acc[c][0][0][2 * Zp];
                #pragma unroll
                for (int o = 0; o < 2; ++o)
                    #pragma unroll
                    for (int p = 0; p < 2; ++p) {
                        m = fmaxf(m, acc[c][o][p][2 * Zp]);
                        m = fmaxf(m, acc[c][o][p][2 * Zp + 1]);
                    }
                const float v = m + bb;
                oP[Zp] = v;
                s0 += v; q0 += v * v;
            }
            atomicAdd(&s_sum[ch], s0); atomicAdd(&s_ssq[ch], q0);
        }
    }
    __syncthreads();
    if (tid < 16) { atomicAdd(&stO[tid], s_sum[tid]); atomicAdd(&stO[16 + tid], s_ssq[tid]); }
}

__global__ __launch_bounds__(256, 3) void k_conv1(const u32* __restrict__ fields,
        const float* __restrict__ w, const float* __restrict__ bias,
        float* __restrict__ a1, float* __restrict__ stO) {
    __shared__ float fldT[48 * 18 * 14];   // 48384 B
    __shared__ u32 wsp[6 * 27 * 8];        // bf16-packed weight pairs, 5184 B
    __shared__ float bs[16], s_sum[16], s_ssq[16];
    const int bx = blockIdx.x, b = bx & 255, sub = bx >> 8, tid = threadIdx.x;
    const int Xg = sub % 3, Zgr = sub / 3;

    for (int i = tid; i < 1296; i += 256) {
        const int c2 = i & 7, t = i >> 3, d = t % 27, ic = t / 27;
        wsp[i] = (u32)f2b(w[(2 * c2) * 162 + ic * 27 + d])
               | ((u32)f2b(w[(2 * c2 + 1) * 162 + ic * 27 + d]) << 16);
    }
    if (tid < 16) { bs[tid] = bias[tid]; s_sum[tid] = 0.0f; s_ssq[tid] = 0.0f; }
    __syncthreads();

    if (Zgr == 0)      conv1_body<0>(b, Xg, tid, fldT, wsp, bs, s_sum, s_ssq, fields, a1, stO);
    else if (Zgr == 1) conv1_body<1>(b, Xg, tid, fldT, wsp, bs, s_sum, s_ssq, fields, a1, stO);
    else               conv1_body<2>(b, Xg, tid, fldT, wsp, bs, s_sum, s_ssq, fields, a1, stO);
}

// ---------- K2: bn1+leaky -> conv2 (16->32, pad0) + pool -> [32,3^3] + bn2 stats
// single block per env, 576 threads = one item each, quad-shuffle 2x2 xy-pool.
__global__ __launch_bounds__(576) void k_conv2(const float* __restrict__ a1,
        const float* __restrict__ w, const float* __restrict__ bias,
        const float* __restrict__ bng, const float* __restrict__ bnb,
        const float* __restrict__ stI, float* __restrict__ a2,
        float* __restrict__ stO) {
    __shared__ float xin[16 * 729];   // 46656 B
    __shared__ float ws2[13824];      // 55296 B
    __shared__ float sc[16], sh[16];
    __shared__ float s_sum[32], s_ssq[32];
    const int b = blockIdx.x, tid = threadIdx.x;
    if (tid < 16) {
        const float cnt = 256.0f * 729.0f;
        float m = stI[tid] / cnt;
        float v = stI[16 + tid] / cnt - m * m;
        float s = bng[tid] * rsqrtf(fmaxf(v, 0.0f) + EPS);
        sc[tid] = s; sh[tid] = bnb[tid] - m * s;
    }
    if (tid < 32) { s_sum[tid] = 0.0f; s_ssq[tid] = 0.0f; }
    __syncthreads();
    const float* src = a1 + (size_t)b * 16 * 729;
    for (int i = tid; i < 16 * 729; i += 576) {
        int c = i / 729;
        xin[i] = leaky(src[i] * sc[c] + sh[c]);
    }
    for (int i = tid; i < 13824; i += 576) ws2[i] = w[i];
    __syncthreads();
    {
        const int oyi = tid & 1, oxi = (tid >> 1) & 1, rest = tid >> 2;
        const int Y = rest % 3, X = (rest / 3) % 3, c2 = rest / 9;   // c2 0..15
        const int ox = 2 * X + oxi, oy = 2 * Y + oyi;   // 0..5
        const int c0 = 2 * c2, c1 = c0 + 1;
        float acc0[6], acc1[6];
        #pragma unroll
        for (int z = 0; z < 6; ++z) { acc0[z] = 0.0f; acc1[z] = 0.0f; }
        for (int ic = 0; ic < 16; ++ic) {
            #pragma unroll
            for (int dx = 0; dx < 3; ++dx) {
                const int ix = ox + dx;
                #pragma unroll
                for (int dy = 0; dy < 3; ++dy) {
                    const int iy = oy + dy;
                    const float* rp = &xin[ic * 729 + ix * 81 + iy * 9];
                    float row[9];
                    #pragma unroll
                    for (int z = 0; z < 9; ++z) row[z] = rp[z];
                    const int wb0 = (c0 * 16 + ic) * 27 + dx * 9 + dy * 3;
                    const int wb1 = (c1 * 16 + ic) * 27 + dx * 9 + dy * 3;
                    #pragma unroll
                    for (int dz = 0; dz < 3; ++dz) {
                        const float w0 = ws2[wb0 + dz];
                        const float w1v = ws2[wb1 + dz];
                        #pragma unroll
                        for (int z = 0; z < 6; ++z) {
                            acc0[z] += w0 * row[z + dz];
                            acc1[z] += w1v * row[z + dz];
                        }
                    }
                }
            }
        }
        float pl[2][3];
        #pragma unroll
        for (int Z = 0; Z < 3; ++Z) {
            float v0 = fmaxf(acc0[2 * Z], acc0[2 * Z + 1]);
            float v1 = fmaxf(acc1[2 * Z], acc1[2 * Z + 1]);
            v0 = fmaxf(v0, __shfl_xor(v0, 1)); v0 = fmaxf(v0, __shfl_xor(v0, 2));
            v1 = fmaxf(v1, __shfl_xor(v1, 1)); v1 = fmaxf(v1, __shfl_xor(v1, 2));
            pl[0][Z] = v0; pl[1][Z] = v1;
        }
        if ((tid & 3) == 0) {
            #pragma unroll
            for (int hh = 0; hh < 2; ++hh) {
                const int c = c0 + hh;
                const float bb = bias[c];
                float s0 = 0.0f, q0 = 0.0f;
                #pragma unroll
                for (int Z = 0; Z < 3; ++Z) {
                    const float v = pl[hh][Z] + bb;
                    a2[((size_t)b * 32 + c) * 27 + X * 9 + Y * 3 + Z] = v;
                    s0 += v; q0 += v * v;
                }
                atomicAdd(&s_sum[c], s0); atomicAdd(&s_ssq[c], q0);
            }
        }
    }
    __syncthreads();
    if (tid < 32) { atomicAdd(&stO[tid], s_sum[tid]); atomicAdd(&stO[32 + tid], s_ssq[tid]); }
}

// ---------- K3: bn2+leaky -> conv3 (32->64, pad1, 3^3) + pool -> [64] + bn3 stats
__global__ __launch_bounds__(256) void k_conv3(const float* __restrict__ a2,
        const float* __restrict__ w, const float* __restrict__ bias,
        const float* __restrict__ bng, const float* __restrict__ bnb,
        const float* __restrict__ stI, float* __restrict__ a3,
        float* __restrict__ stO) {
    __shared__ float x[864];
    __shared__ float pacc[256 * 8];
    __shared__ float sc[32], sh[32];
    const int b = blockIdx.x, tid = threadIdx.x;
    if (tid < 32) {
        const float cnt = 256.0f * 27.0f;
        float m = stI[tid] / cnt;
        float v = stI[32 + tid] / cnt - m * m;
        float s = bng[tid] * rsqrtf(fmaxf(v, 0.0f) + EPS);
        sc[tid] = s; sh[tid] = bnb[tid] - m * s;
    }
    __syncthreads();
    for (int i = tid; i < 864; i += 256) {
        int c = i / 27;
        x[i] = leaky(a2[(size_t)b * 864 + i] * sc[c] + sh[c]);
    }
    __syncthreads();
    const int c = tid & 63, q = tid >> 6;
    float acc[8];
    #pragma unroll
    for (int p = 0; p < 8; ++p) acc[p] = 0.0f;
    for (int ic = q * 8; ic < q * 8 + 8; ++ic) {
        const float* wr = w + ((size_t)c * 32 + ic) * 27;
        #pragma unroll
        for (int d = 0; d < 27; ++d) {
            const int dx = d / 9, dy = (d / 3) % 3, dz = d % 3;
            const float wv = wr[d];
            #pragma unroll
            for (int p = 0; p < 8; ++p) {
                const int px = p >> 2, py = (p >> 1) & 1, pz = p & 1;
                const int ix = px + dx - 1, iy = py + dy - 1, iz = pz + dz - 1;
                if (ix >= 0 && iy >= 0 && iz >= 0)
                    acc[p] += wv * x[ic * 27 + ix * 9 + iy * 3 + iz];
            }
        }
    }
    #pragma unroll
    for (int p = 0; p < 8; ++p) pacc[tid * 8 + p] = acc[p];
    __syncthreads();
    if (q == 0) {
        float m = -1e30f;
        #pragma unroll
        for (int p = 0; p < 8; ++p) {
            float v = pacc[c * 8 + p] + pacc[(64 + c) * 8 + p]
                    + pacc[(128 + c) * 8 + p] + pacc[(192 + c) * 8 + p];
            m = fmaxf(m, v);
        }
        float v = m + bias[c];
        a3[(size_t)b * 64 + c] = v;
        atomicAdd(&stO[c], v); atomicAdd(&stO[64 + c], v * v);
    }
}

// ---------- K4: bn3+leaky -> dense 64->128 (pre-bn4) + bn4 stats
__global__ __launch_bounds__(128) void k_dense1(const float* __restrict__ a3,
        const float* __restrict__ bng, const float* __restrict__ bnb,
        const float* __restrict__ stI,
        const float* __restrict__ w1, const float* __restrict__ b1,
        float* __restrict__ h1, float* __restrict__ stO) {
    __shared__ float x[64];
    const int b = blockIdx.x, tid = threadIdx.x;
    if (tid < 64) {
        float m = stI[tid] / 256.0f;
        float v = stI[64 + tid] / 256.0f - m * m;
        float s = bng[tid] * rsqrtf(fmaxf(v, 0.0f) + EPS);
        x[tid] = leaky(a3[(size_t)b * 64 + tid] * s + (bnb[tid] - m * s));
    }
    __syncthreads();
    const float* wr = w1 + tid * 64;
    float acc = b1[tid];
    #pragma unroll
    for (int i = 0; i < 64; ++i) acc += x[i] * wr[i];
    h1[(size_t)b * 128 + tid] = acc;
    atomicAdd(&stO[tid], acc); atomicAdd(&stO[128 + tid], acc * acc);
}

// ---------- K5: bn4+leaky -> 128->100 (+leaky) -> 100->20 -> out (f32)
__global__ __launch_bounds__(128) void k_dense2(const float* __restrict__ h1,
        const float* __restrict__ bng, const float* __restrict__ bnb,
        const float* __restrict__ stI,
        const float* __restrict__ w2, const float* __restrict__ bias2,
        const float* __restrict__ w3, const float* __restrict__ bias3,
        float* __restrict__ out) {
    __shared__ float x[128];
    __shared__ float y[100];
    const int b = blockIdx.x, tid = threadIdx.x;
    {
        float m = stI[tid] / 256.0f;
        float v = stI[128 + tid] / 256.0f - m * m;
        float s = bng[tid] * rsqrtf(fmaxf(v, 0.0f) + EPS);
        x[tid] = leaky(h1[(size_t)b * 128 + tid] * s + (bnb[tid] - m * s));
    }
    __syncthreads();
    if (tid < 100) {
        const float* wr = w2 + tid * 128;
        float acc = bias2[tid];
        #pragma unroll
        for (int i = 0; i < 128; ++i) acc += x[i] * wr[i];
        y[tid] = leaky(acc);
    }
    __syncthreads();
    if (tid < 20) {
        const float* wr = w3 + tid * 100;
        float acc = bias3[tid];
        #pragma unroll
        for (int i = 0; i < 100; ++i) acc += y[i] * wr[i];
        out[(size_t)b * 20 + tid] = acc;
    }
}

extern "C" void kernel_launch(void* const* d_in, const int* in_sizes, int n_in,
                              void* d_out, int out_size, void* d_ws, size_t ws_size,
                              hipStream_t stream) {
    (void)in_sizes; (void)n_in; (void)out_size; (void)ws_size;
    const float* pos  = (const float*)d_in[0];
    const float* c1w  = (const float*)d_in[1];
    const float* c1b  = (const float*)d_in[2];
    const float* bn1g = (const float*)d_in[3];
    const float* bn1b = (const float*)d_in[4];
    const float* c2w  = (const float*)d_in[5];
    const float* c2b  = (const float*)d_in[6];
    const float* bn2g = (const float*)d_in[7];
    const float* bn2b = (const float*)d_in[8];
    const float* c3w  = (const float*)d_in[9];
    const float* c3b  = (const float*)d_in[10];
    const float* bn3g = (const float*)d_in[11];
    const float* bn3b = (const float*)d_in[12];
    const float* d1w  = (const float*)d_in[13];
    const float* d1b  = (const float*)d_in[14];
    const float* bn4g = (const float*)d_in[15];
    const float* bn4b = (const float*)d_in[16];
    const float* d2w  = (const float*)d_in[17];
    const float* d2b  = (const float*)d_in[18];
    const float* d3w  = (const float*)d_in[19];
    const float* d3b  = (const float*)d_in[20];
    const int* types  = (const int*)d_in[22];   // d_in[21]=batch_ids implied by layout

    float* ws = (float*)d_ws;
    float* st = ws;                         // 480 f (bn stats)
    float* a3 = ws + 512;                   // 16,384 f
    float* h1 = a3 + 16384;                 // 32,768 f
    float* a2 = h1 + 32768;                 // 221,184 f
    float* a1 = a2 + 221184;                // 2,985,984 f
    u32* fields = (u32*)(a1 + 2985984);     // bf16 pairs: 4,478,976 u32 (~31 MB total)

    hipMemsetAsync(st, 0, 480 * sizeof(float), stream);
    k_splat <<<2 * BATCH, 512, 0, stream>>>(pos, types, fields);
    k_conv1 <<<9 * BATCH, 256, 0, stream>>>(fields, c1w, c1b, a1, st);
    k_conv2 <<<BATCH, 576, 0, stream>>>(a1, c2w, c2b, bn1g, bn1b, st, a2, st + 32);
    k_conv3 <<<BATCH, 256, 0, stream>>>(a2, c3w, c3b, bn2g, bn2b, st + 32, a3, st + 96);
    k_dense1<<<BATCH, 128, 0, stream>>>(a3, bn3g, bn3b, st + 96, d1w, d1b, h1, st + 224);
    k_dense2<<<BATCH, 128, 0, stream>>>(h1, bn4g, bn4b, st + 224, d2w, d2b, d3w, d3b,
                                        (float*)d_out);
}

// Round 6
// 367.518 us; speedup vs baseline: 1.5861x; 1.5861x over previous
//
#include <hip/hip_runtime.h>

// CavityModel forward: gaussian blur -> 3x(conv3d+maxpool+BN(batch stats)+leaky)
// -> dense 64->128 (+BN+leaky) -> 128->100 (+leaky) -> 100->20.
// R6: conv1 full-z tile (one coalesced stage, 3 register Zg passes), a1 layout
// [b][spatial][ch] for packed 64B writes, same-env blocks dispatch-adjacent.

#define G2 324
#define G3 5832
#define NT 6
#define BATCH 256
#define APE 100
#define EPS 1e-5f

typedef unsigned short u16;
typedef unsigned int u32;

__device__ __forceinline__ float leaky(float x) { return x >= 0.0f ? x : 0.01f * x; }
__device__ __forceinline__ u16 f2b(float f) {
    union { float f; u32 u; } v; v.f = f;
    return (u16)((v.u + 0x7FFFu + ((v.u >> 16) & 1u)) >> 16);
}
__device__ __forceinline__ float b2f(u16 u) {
    union { u32 u; float f; } v; v.u = ((u32)u) << 16; return v.f;
}

// ---------- K1a: gaussian splat, type-split: block = (env, type-triple h)
// field half [3][18^3] in LDS (70 KB); output bf16 pairs.
__global__ __launch_bounds__(512) void k_splat(const float* __restrict__ pos,
        const int* __restrict__ types, u32* __restrict__ fields) {
    __shared__ float fld[3 * G3];    // 69984 B
    __shared__ float ew[64 * 27];
    __shared__ short i0a[64 * 3];
    __shared__ int al[64];
    __shared__ int cnt;
    const int bx = blockIdx.x, b = bx & 255, h = bx >> 8, tid = threadIdx.x;

    float4* f4 = (float4*)fld;
    for (int i = tid; i < 3 * G3 / 4; i += 512) f4[i] = make_float4(0, 0, 0, 0);
    if (tid == 0) cnt = 0;
    __syncthreads();
    if (tid < APE) {
        const int t = types[b * APE + tid];
        if (t >= 3 * h && t < 3 * h + 3) {
            const int j = atomicAdd(&cnt, 1);
            if (j < 64) al[j] = tid | ((t - 3 * h) << 16);
        }
    }
    __syncthreads();
    const int NA = min(cnt, 64);
    if (tid < 3 * NA) {
        const int la = tid / 3, ax = tid % 3;
        const int n = b * APE + (al[la] & 0xffff);
        const float p = pos[n * 3 + ax];
        int i0 = (int)ceilf(p + 4.0f);
        i0 = max(0, min(9, i0));
        i0a[la * 3 + ax] = (short)i0;
        float e[18], s = 0.0f;
        #pragma unroll
        for (int g = 0; g < 18; ++g) {
            float d = (float)g - 8.5f - p;
            e[g] = __expf(d * d * (-1.0f / 0.72f));
            s += e[g];
        }
        const float inv = 1.0f / s;
        #pragma unroll
        for (int q = 0; q < 9; ++q) ew[la * 27 + ax * 9 + q] = e[i0 + q] * inv;
    }
    __syncthreads();
    for (int idx = tid; idx < NA * 729; idx += 512) {
        const int la = idx / 729, r = idx % 729;
        const int di = r / 81, dj = (r / 9) % 9, dk = r % 9;
        const int a = al[la];
        atomicAdd(&fld[(a >> 16) * G3 + (i0a[la * 3] + di) * G2
                       + (i0a[la * 3 + 1] + dj) * 18 + (i0a[la * 3 + 2] + dk)],
                  ew[la * 27 + di] * ew[la * 27 + 9 + dj] * ew[la * 27 + 18 + dk]);
    }
    __syncthreads();
    u32* dst = fields + ((size_t)b * 6 + 3 * h) * (G3 / 2);
    for (int i = tid; i < 3 * G3 / 2; i += 512)
        dst[i] = (u32)f2b(fld[2 * i]) | ((u32)f2b(fld[2 * i + 1]) << 16);
}

// ---------- K1b: conv1 (6->16, pad1) + 2x2x2 maxpool + bias + bn1 stats
// block = (env, Xg 0..2), grid bx = b*3+Xg (same-env adjacent).
// Stage full-z tile [48 planes][18 y][20 z(pad)] once, coalesced 648B z-runs.
// Thread = sp*8 + c2 (c2 fastest); 3 register Zg passes over the same tile.
// a1 layout: [b][spatial 729][ch 16] -> pool-triple writes are packed 64B lines.
__global__ __launch_bounds__(256, 2) void k_conv1(const u32* __restrict__ fields,
        const float* __restrict__ w, const float* __restrict__ bias,
        float* __restrict__ a1, float* __restrict__ stO) {
    __shared__ float fldT[48 * 18 * 20];   // 69120 B; row idx = z+1 (z=-1,18 pads)
    __shared__ u32 wsp[6 * 27 * 8];        // bf16-packed channel pairs, 5184 B
    __shared__ float bs[16], s_sum[16], s_ssq[16];
    const int bx = blockIdx.x, b = bx / 3, Xg = bx % 3, tid = threadIdx.x;

    for (int i = tid; i < 1296; i += 256) {
        const int c2 = i & 7, t = i >> 3, d = t % 27, ic = t / 27;
        wsp[i] = (u32)f2b(w[(2 * c2) * 162 + ic * 27 + d])
               | ((u32)f2b(w[(2 * c2 + 1) * 162 + ic * 27 + d]) << 16);
    }
    if (tid < 16) { bs[tid] = bias[tid]; s_sum[tid] = 0.0f; s_ssq[tid] = 0.0f; }

    // stage: 48 (ic,ixl) planes x 18 iy x 9 z-pairs, contiguous per plane
    for (int i = tid; i < 7776; i += 256) {
        const int a = i / 162, rem = i % 162;      // a = ic*8 + ixl
        const int iy = rem / 9, p = rem % 9;
        const int ix = 6 * Xg - 1 + (a & 7);
        u32 v = 0;
        if (ix >= 0 && ix < 18)
            v = fields[((size_t)(b * 6 + (a >> 3)) * 18 + ix) * 162 + rem];
        const int base = (a * 18 + iy) * 20 + 1 + 2 * p;
        fldT[base] = b2f((u16)v);
        fldT[base + 1] = b2f((u16)(v >> 16));
        if (p == 0) fldT[base - 1] = 0.0f;        // z = -1 pad
        if (p == 8) fldT[base + 2] = 0.0f;        // z = 18 pad
    }
    __syncthreads();

    const int c2 = tid & 7, sp = tid >> 3;         // sp 0..26 active
    const int Xl = sp / 9, Y = sp % 9;
    if (tid < 216) {
        for (int Zg = 0; Zg < 3; ++Zg) {
            float acc[2][2][2][6];
            #pragma unroll
            for (int c = 0; c < 2; ++c)
                #pragma unroll
                for (int o = 0; o < 2; ++o)
                    #pragma unroll
                    for (int p = 0; p < 2; ++p)
                        #pragma unroll
                        for (int z = 0; z < 6; ++z) acc[c][o][p][z] = 0.0f;

            for (int ic = 0; ic < 6; ++ic) {
                float wreg[2][27];
                #pragma unroll
                for (int d = 0; d < 27; ++d) {
                    const u32 pw = wsp[(ic * 27 + d) * 8 + c2];
                    wreg[0][d] = b2f((u16)pw);
                    wreg[1][d] = b2f((u16)(pw >> 16));
                }
                #pragma unroll
                for (int lj = 0; lj < 4; ++lj) {
                    const int iy = 2 * Y + lj - 1;
                    const bool yok = (iy >= 0 && iy < 18);
                    #pragma unroll
                    for (int li = 0; li < 4; ++li) {
                        const int ixl = 2 * Xl + li;
                        float row[8];
                        if (yok) {
                            const float2* rp = (const float2*)
                                &fldT[(((ic << 3) + ixl) * 18 + iy) * 20 + 6 * Zg];
                            #pragma unroll
                            for (int q = 0; q < 4; ++q) {
                                const float2 t2 = rp[q];
                                row[2 * q] = t2.x; row[2 * q + 1] = t2.y;
                            }
                        } else {
                            #pragma unroll
                            for (int z = 0; z < 8; ++z) row[z] = 0.0f;
                        }
                        #pragma unroll
                        for (int o = 0; o < 2; ++o) {
                            const int dx = li - o;
                            if (dx < 0 || dx > 2) continue;
                            #pragma unroll
                            for (int p = 0; p < 2; ++p) {
                                const int dy = lj - p;
                                if (dy < 0 || dy > 2) continue;
                                const int wd = dx * 9 + dy * 3;
                                #pragma unroll
                                for (int dz = 0; dz < 3; ++dz) {
                                    const float w0 = wreg[0][wd + dz];
                                    const float w1 = wreg[1][wd + dz];
                                    #pragma unroll
                                    for (int oz = 0; oz < 6; ++oz) {
                                        const float rv = row[oz + dz];
                                        acc[0][o][p][oz] += w0 * rv;
                                        acc[1][o][p][oz] += w1 * rv;
                                    }
                                }
                            }
                        }
                    }
                }
            }
            // 2x2x2 pool in-register + bias; packed float2 write to [sp][16]
            float s0[2] = {0.0f, 0.0f}, q0[2] = {0.0f, 0.0f};
            #pragma unroll
            for (int Zp = 0; Zp < 3; ++Zp) {
                float2 vv;
                #pragma unroll
                for (int c = 0; c < 2; ++c) {
                    float m = acc[c][0][0][2 * Zp];
                    #pragma unroll
                    for (int o = 0; o < 2; ++o)
                        #pragma unroll
                        for (int p = 0; p < 2; ++p) {
                            m = fmaxf(m, acc[c][o][p][2 * Zp]);
                            m = fmaxf(m, acc[c][o][p][2 * Zp + 1]);
                        }
                    const float v = m + bs[2 * c2 + c];
                    (c ? vv.y : vv.x) = v;
                    s0[c] += v; q0[c] += v * v;
                }
                const int spg = (3 * Xg + Xl) * 81 + Y * 9 + 3 * Zg + Zp;
                *(float2*)&a1[((size_t)b * 729 + spg) * 16 + 2 * c2] = vv;
            }
            #pragma unroll
            for (int c = 0; c < 2; ++c) {
                atomicAdd(&s_sum[2 * c2 + c], s0[c]);
                atomicAdd(&s_ssq[2 * c2 + c], q0[c]);
            }
        }
    }
    __syncthreads();
    if (tid < 16) { atomicAdd(&stO[tid], s_sum[tid]); atomicAdd(&stO[16 + tid], s_ssq[tid]); }
}

// ---------- K2: bn1+leaky -> conv2 (16->32, pad0) + pool -> [32,3^3] + bn2 stats
// single block per env, 576 threads; a1 read in [spatial][ch] layout.
__global__ __launch_bounds__(576) void k_conv2(const float* __restrict__ a1,
        const float* __restrict__ w, const float* __restrict__ bias,
        const float* __restrict__ bng, const float* __restrict__ bnb,
        const float* __restrict__ stI, float* __restrict__ a2,
        float* __restrict__ stO) {
    __shared__ float xin[16 * 729];   // 46656 B
    __shared__ float ws2[13824];      // 55296 B
    __shared__ float sc[16], sh[16];
    __shared__ float s_sum[32], s_ssq[32];
    const int b = blockIdx.x, tid = threadIdx.x;
    if (tid < 16) {
        const float cnt = 256.0f * 729.0f;
        float m = stI[tid] / cnt;
        float v = stI[16 + tid] / cnt - m * m;
        float s = bng[tid] * rsqrtf(fmaxf(v, 0.0f) + EPS);
        sc[tid] = s; sh[tid] = bnb[tid] - m * s;
    }
    if (tid < 32) { s_sum[tid] = 0.0f; s_ssq[tid] = 0.0f; }
    __syncthreads();
    const float* src = a1 + (size_t)b * 729 * 16;
    for (int i = tid; i < 16 * 729; i += 576) {
        const int spb = i >> 4, c = i & 15;
        xin[c * 729 + spb] = leaky(src[i] * sc[c] + sh[c]);
    }
    for (int i = tid; i < 13824; i += 576) ws2[i] = w[i];
    __syncthreads();
    {
        const int oyi = tid & 1, oxi = (tid >> 1) & 1, rest = tid >> 2;
        const int Y = rest % 3, X = (rest / 3) % 3, c2 = rest / 9;   // c2 0..15
        const int ox = 2 * X + oxi, oy = 2 * Y + oyi;   // 0..5
        const int c0 = 2 * c2, c1 = c0 + 1;
        float acc0[6], acc1[6];
        #pragma unroll
        for (int z = 0; z < 6; ++z) { acc0[z] = 0.0f; acc1[z] = 0.0f; }
        for (int ic = 0; ic < 16; ++ic) {
            #pragma unroll
            for (int dx = 0; dx < 3; ++dx) {
                const int ix = ox + dx;
                #pragma unroll
                for (int dy = 0; dy < 3; ++dy) {
                    const int iy = oy + dy;
                    const float* rp = &xin[ic * 729 + ix * 81 + iy * 9];
                    float row[9];
                    #pragma unroll
                    for (int z = 0; z < 9; ++z) row[z] = rp[z];
                    const int wb0 = (c0 * 16 + ic) * 27 + dx * 9 + dy * 3;
                    const int wb1 = (c1 * 16 + ic) * 27 + dx * 9 + dy * 3;
                    #pragma unroll
                    for (int dz = 0; dz < 3; ++dz) {
                        const float w0 = ws2[wb0 + dz];
                        const float w1v = ws2[wb1 + dz];
                        #pragma unroll
                        for (int z = 0; z < 6; ++z) {
                            acc0[z] += w0 * row[z + dz];
                            acc1[z] += w1v * row[z + dz];
                        }
                    }
                }
            }
        }
        float pl[2][3];
        #pragma unroll
        for (int Z = 0; Z < 3; ++Z) {
            float v0 = fmaxf(acc0[2 * Z], acc0[2 * Z + 1]);
            float v1 = fmaxf(acc1[2 * Z], acc1[2 * Z + 1]);
            v0 = fmaxf(v0, __shfl_xor(v0, 1)); v0 = fmaxf(v0, __shfl_xor(v0, 2));
            v1 = fmaxf(v1, __shfl_xor(v1, 1)); v1 = fmaxf(v1, __shfl_xor(v1, 2));
            pl[0][Z] = v0; pl[1][Z] = v1;
        }
        if ((tid & 3) == 0) {
            #pragma unroll
            for (int hh = 0; hh < 2; ++hh) {
                const int c = c0 + hh;
                const float bb = bias[c];
                float s0 = 0.0f, q0 = 0.0f;
                #pragma unroll
                for (int Z = 0; Z < 3; ++Z) {
                    const float v = pl[hh][Z] + bb;
                    a2[((size_t)b * 32 + c) * 27 + X * 9 + Y * 3 + Z] = v;
                    s0 += v; q0 += v * v;
                }
                atomicAdd(&s_sum[c], s0); atomicAdd(&s_ssq[c], q0);
            }
        }
    }
    __syncthreads();
    if (tid < 32) { atomicAdd(&stO[tid], s_sum[tid]); atomicAdd(&stO[32 + tid], s_ssq[tid]); }
}

// ---------- K3: bn2+leaky -> conv3 (32->64, pad1, 3^3) + pool -> [64] + bn3 stats
__global__ __launch_bounds__(256) void k_conv3(const float* __restrict__ a2,
        const float* __restrict__ w, const float* __restrict__ bias,
        const float* __restrict__ bng, const float* __restrict__ bnb,
        const float* __restrict__ stI, float* __restrict__ a3,
        float* __restrict__ stO) {
    __shared__ float x[864];
    __shared__ float pacc[256 * 8];
    __shared__ float sc[32], sh[32];
    const int b = blockIdx.x, tid = threadIdx.x;
    if (tid < 32) {
        const float cnt = 256.0f * 27.0f;
        float m = stI[tid] / cnt;
        float v = stI[32 + tid] / cnt - m * m;
        float s = bng[tid] * rsqrtf(fmaxf(v, 0.0f) + EPS);
        sc[tid] = s; sh[tid] = bnb[tid] - m * s;
    }
    __syncthreads();
    for (int i = tid; i < 864; i += 256) {
        int c = i / 27;
        x[i] = leaky(a2[(size_t)b * 864 + i] * sc[c] + sh[c]);
    }
    __syncthreads();
    const int c = tid & 63, q = tid >> 6;
    float acc[8];
    #pragma unroll
    for (int p = 0; p < 8; ++p) acc[p] = 0.0f;
    for (int ic = q * 8; ic < q * 8 + 8; ++ic) {
        const float* wr = w + ((size_t)c * 32 + ic) * 27;
        #pragma unroll
        for (int d = 0; d < 27; ++d) {
            const int dx = d / 9, dy = (d / 3) % 3, dz = d % 3;
            const float wv = wr[d];
            #pragma unroll
            for (int p = 0; p < 8; ++p) {
                const int px = p >> 2, py = (p >> 1) & 1, pz = p & 1;
                const int ix = px + dx - 1, iy = py + dy - 1, iz = pz + dz - 1;
                if (ix >= 0 && iy >= 0 && iz >= 0)
                    acc[p] += wv * x[ic * 27 + ix * 9 + iy * 3 + iz];
            }
        }
    }
    #pragma unroll
    for (int p = 0; p < 8; ++p) pacc[tid * 8 + p] = acc[p];
    __syncthreads();
    if (q == 0) {
        float m = -1e30f;
        #pragma unroll
        for (int p = 0; p < 8; ++p) {
            float v = pacc[c * 8 + p] + pacc[(64 + c) * 8 + p]
                    + pacc[(128 + c) * 8 + p] + pacc[(192 + c) * 8 + p];
            m = fmaxf(m, v);
        }
        float v = m + bias[c];
        a3[(size_t)b * 64 + c] = v;
        atomicAdd(&stO[c], v); atomicAdd(&stO[64 + c], v * v);
    }
}

// ---------- K4: bn3+leaky -> dense 64->128 (pre-bn4) + bn4 stats
__global__ __launch_bounds__(128) void k_dense1(const float* __restrict__ a3,
        const float* __restrict__ bng, const float* __restrict__ bnb,
        const float* __restrict__ stI,
        const float* __restrict__ w1, const float* __restrict__ b1,
        float* __restrict__ h1, float* __restrict__ stO) {
    __shared__ float x[64];
    const int b = blockIdx.x, tid = threadIdx.x;
    if (tid < 64) {
        float m = stI[tid] / 256.0f;
        float v = stI[64 + tid] / 256.0f - m * m;
        float s = bng[tid] * rsqrtf(fmaxf(v, 0.0f) + EPS);
        x[tid] = leaky(a3[(size_t)b * 64 + tid] * s + (bnb[tid] - m * s));
    }
    __syncthreads();
    const float* wr = w1 + tid * 64;
    float acc = b1[tid];
    #pragma unroll
    for (int i = 0; i < 64; ++i) acc += x[i] * wr[i];
    h1[(size_t)b * 128 + tid] = acc;
    atomicAdd(&stO[tid], acc); atomicAdd(&stO[128 + tid], acc * acc);
}

// ---------- K5: bn4+leaky -> 128->100 (+leaky) -> 100->20 -> out (f32)
__global__ __launch_bounds__(128) void k_dense2(const float* __restrict__ h1,
        const float* __restrict__ bng, const float* __restrict__ bnb,
        const float* __restrict__ stI,
        const float* __restrict__ w2, const float* __restrict__ bias2,
        const float* __restrict__ w3, const float* __restrict__ bias3,
        float* __restrict__ out) {
    __shared__ float x[128];
    __shared__ float y[100];
    const int b = blockIdx.x, tid = threadIdx.x;
    {
        float m = stI[tid] / 256.0f;
        float v = stI[128 + tid] / 256.0f - m * m;
        float s = bng[tid] * rsqrtf(fmaxf(v, 0.0f) + EPS);
        x[tid] = leaky(h1[(size_t)b * 128 + tid] * s + (bnb[tid] - m * s));
    }
    __syncthreads();
    if (tid < 100) {
        const float* wr = w2 + tid * 128;
        float acc = bias2[tid];
        #pragma unroll
        for (int i = 0; i < 128; ++i) acc += x[i] * wr[i];
        y[tid] = leaky(acc);
    }
    __syncthreads();
    if (tid < 20) {
        const float* wr = w3 + tid * 100;
        float acc = bias3[tid];
        #pragma unroll
        for (int i = 0; i < 100; ++i) acc += y[i] * wr[i];
        out[(size_t)b * 20 + tid] = acc;
    }
}

extern "C" void kernel_launch(void* const* d_in, const int* in_sizes, int n_in,
                              void* d_out, int out_size, void* d_ws, size_t ws_size,
                              hipStream_t stream) {
    (void)in_sizes; (void)n_in; (void)out_size; (void)ws_size;
    const float* pos  = (const float*)d_in[0];
    const float* c1w  = (const float*)d_in[1];
    const float* c1b  = (const float*)d_in[2];
    const float* bn1g = (const float*)d_in[3];
    const float* bn1b = (const float*)d_in[4];
    const float* c2w  = (const float*)d_in[5];
    const float* c2b  = (const float*)d_in[6];
    const float* bn2g = (const float*)d_in[7];
    const float* bn2b = (const float*)d_in[8];
    const float* c3w  = (const float*)d_in[9];
    const float* c3b  = (const float*)d_in[10];
    const float* bn3g = (const float*)d_in[11];
    const float* bn3b = (const float*)d_in[12];
    const float* d1w  = (const float*)d_in[13];
    const float* d1b  = (const float*)d_in[14];
    const float* bn4g = (const float*)d_in[15];
    const float* bn4b = (const float*)d_in[16];
    const float* d2w  = (const float*)d_in[17];
    const float* d2b  = (const float*)d_in[18];
    const float* d3w  = (const float*)d_in[19];
    const float* d3b  = (const float*)d_in[20];
    const int* types  = (const int*)d_in[22];   // d_in[21]=batch_ids implied by layout

    float* ws = (float*)d_ws;
    float* st = ws;                         // 480 f (bn stats)
    float* a3 = ws + 512;                   // 16,384 f
    float* h1 = a3 + 16384;                 // 32,768 f
    float* a2 = h1 + 32768;                 // 221,184 f
    float* a1 = a2 + 221184;                // 2,985,984 f  [b][729][16]
    u32* fields = (u32*)(a1 + 2985984);     // bf16 pairs: 4,478,976 u32 (~31 MB total)

    hipMemsetAsync(st, 0, 480 * sizeof(float), stream);
    k_splat <<<2 * BATCH, 512, 0, stream>>>(pos, types, fields);
    k_conv1 <<<3 * BATCH, 256, 0, stream>>>(fields, c1w, c1b, a1, st);
    k_conv2 <<<BATCH, 576, 0, stream>>>(a1, c2w, c2b, bn1g, bn1b, st, a2, st + 32);
    k_conv3 <<<BATCH, 256, 0, stream>>>(a2, c3w, c3b, bn2g, bn2b, st + 32, a3, st + 96);
    k_dense1<<<BATCH, 128, 0, stream>>>(a3, bn3g, bn3b, st + 96, d1w, d1b, h1, st + 224);
    k_dense2<<<BATCH, 128, 0, stream>>>(h1, bn4g, bn4b, st + 224, d2w, d2b, d3w, d3b,
                                        (float*)d_out);
}

// Round 7
// 236.810 us; speedup vs baseline: 2.4615x; 1.5520x over previous
//
#include <hip/hip_runtime.h>

// CavityModel forward: gaussian blur -> 3x(conv3d+maxpool+BN(batch stats)+leaky)
// -> dense 64->128 (+BN+leaky) -> 128->100 (+leaky) -> 100->20.
// R7: splat = atomic-free separable outer-product (exact normalization);
// conv1 = f16 fields + v_dot2_f32_f16 inner loop, 40KB LDS -> 3 blocks/CU.

#define G2 324
#define G3 5832
#define NT 6
#define BATCH 256
#define APE 100
#define EPS 1e-5f

typedef unsigned short u16;
typedef unsigned int u32;
typedef _Float16 h2 __attribute__((ext_vector_type(2)));

__device__ __forceinline__ float leaky(float x) { return x >= 0.0f ? x : 0.01f * x; }
__device__ __forceinline__ u32 pkh(float a, float b) {
    h2 v; v[0] = (_Float16)a; v[1] = (_Float16)b;
    return __builtin_bit_cast(u32, v);
}
__device__ __forceinline__ float fdot2u(u32 a, u32 b, float c) {
#if __has_builtin(__builtin_amdgcn_fdot2)
    return __builtin_amdgcn_fdot2(__builtin_bit_cast(h2, a),
                                  __builtin_bit_cast(h2, b), c, false);
#else
    h2 x = __builtin_bit_cast(h2, a), y = __builtin_bit_cast(h2, b);
    return c + (float)x[0] * (float)y[0] + (float)x[1] * (float)y[1];
#endif
}

// ---------- K1a: gaussian splat, separable outer product, NO atomics.
// thread item = (t,i,j): acc[18] over atoms of type t; exact full-grid norm.
// fields: f16 pairs, u32 word = (z_{2p}, z_{2p+1}), 9 words per (t,i,j) row.
__global__ __launch_bounds__(512) void k_splat(const float* __restrict__ pos,
        const int* __restrict__ types, u32* __restrict__ fields) {
    __shared__ float ew[APE * 54];     // [atom][axis][18]; axis0 has 1/(SxSySz)
    __shared__ float ssum[APE * 3];
    __shared__ int list[APE];
    __shared__ int base[NT + 1];
    __shared__ int cnt[NT], cur[NT];
    const int b = blockIdx.x, tid = threadIdx.x;

    if (tid < NT) { cnt[tid] = 0; cur[tid] = 0; }
    __syncthreads();
    if (tid < APE) atomicAdd(&cnt[types[b * APE + tid]], 1);
    if (tid < 300) {
        const int la = tid / 3, ax = tid % 3;
        const float p = pos[(b * APE + la) * 3 + ax];
        float s = 0.0f;
        #pragma unroll
        for (int g = 0; g < 18; ++g) {
            const float d = (float)g - 8.5f - p;
            const float e = __expf(d * d * (-1.0f / 0.72f));
            ew[la * 54 + ax * 18 + g] = e;
            s += e;
        }
        ssum[tid] = s;
    }
    __syncthreads();
    if (tid == 0) {
        int s = 0;
        #pragma unroll
        for (int t = 0; t < NT; ++t) { base[t] = s; s += cnt[t]; }
        base[NT] = s;
    }
    if (tid < APE) {
        const float inv = 1.0f / (ssum[tid * 3] * ssum[tid * 3 + 1] * ssum[tid * 3 + 2]);
        #pragma unroll
        for (int g = 0; g < 18; ++g) ew[tid * 54 + g] *= inv;
    }
    __syncthreads();
    if (tid < APE) {
        const int t = types[b * APE + tid];
        const int j = atomicAdd(&cur[t], 1);
        list[base[t] + j] = tid;
    }
    __syncthreads();

    for (int it = tid; it < NT * 324; it += 512) {
        const int t = it / 324, r = it - t * 324;
        const int i = r / 18, j = r % 18;
        float acc[18];
        #pragma unroll
        for (int k = 0; k < 18; ++k) acc[k] = 0.0f;
        const int e1 = base[t + 1];
        for (int u = base[t]; u < e1; ++u) {
            const int a = list[u];
            const float exy = ew[a * 54 + i] * ew[a * 54 + 18 + j];
            const float* ez = &ew[a * 54 + 36];
            #pragma unroll
            for (int k = 0; k < 18; ++k) acc[k] += exy * ez[k];
        }
        u32* dst = &fields[((size_t)b * NT + t) * 2916 + (size_t)r * 9];
        #pragma unroll
        for (int q = 0; q < 9; ++q) dst[q] = pkh(acc[2 * q], acc[2 * q + 1]);
    }
}

// ---------- K1b: conv1 (6->16, pad1) + 2x2x2 maxpool + bias + bn1 stats
// block = (env, Xg 0..2); stage f16 tile [48 planes][18 iy][10 words] (word9=0);
// thread = sp*8+c2 (216 active); 3 register ZG passes; fdot2 z-pairs.
// a1 layout [b][spatial 729][ch 16], packed float2 writes.
template <int ZG>
__device__ __forceinline__ void conv1_pass(int c2, int Xl, int Yv, int b, int Xg,
        const u32* fldH, const u32* wpk, float* s_sum, float* s_ssq,
        const float* __restrict__ bias, float* __restrict__ a1) {
    float acc[2][2][2][6];
    #pragma unroll
    for (int c = 0; c < 2; ++c)
        #pragma unroll
        for (int o = 0; o < 2; ++o)
            #pragma unroll
            for (int p = 0; p < 2; ++p)
                #pragma unroll
                for (int z = 0; z < 6; ++z) acc[c][o][p][z] = 0.0f;

    for (int ic = 0; ic < 6; ++ic) {
        u32 A0[9], A1[9], Be0[9], Be1[9];
        #pragma unroll
        for (int d2 = 0; d2 < 9; ++d2) {
            const int wb = ((ic * 9 + d2) * 8 + c2) * 3;
            A0[d2] = wpk[wb]; A1[d2] = wpk[wb + 1];
            const u32 w2 = wpk[wb + 2];
            Be0[d2] = w2 & 0xFFFFu; Be1[d2] = w2 >> 16;
        }
        #pragma unroll
        for (int lj = 0; lj < 4; ++lj) {
            const int iy = 2 * Yv + lj - 1;
            const bool yok = (iy >= 0 && iy < 18);
            #pragma unroll
            for (int li = 0; li < 4; ++li) {
                const int ixl = 2 * Xl + li;
                u32 V[5], Sh[4];
                if (yok) {
                    const u32* rp = &fldH[((ic * 8 + ixl) * 18 + iy) * 10];
                    if (ZG == 0) {
                        V[0] = 0u;
                        #pragma unroll
                        for (int q = 0; q < 4; ++q) V[q + 1] = rp[q];
                    } else {
                        #pragma unroll
                        for (int q = 0; q < 5; ++q) V[q] = rp[3 * ZG - 1 + q];
                    }
                } else {
                    #pragma unroll
                    for (int q = 0; q < 5; ++q) V[q] = 0u;
                }
                #pragma unroll
                for (int q = 0; q < 4; ++q)
                    Sh[q] = __builtin_amdgcn_alignbit(V[q + 1], V[q], 16);
                #pragma unroll
                for (int o = 0; o < 2; ++o) {
                    const int dx = li - o;
                    if (dx < 0 || dx > 2) continue;
                    #pragma unroll
                    for (int p = 0; p < 2; ++p) {
                        const int dy = lj - p;
                        if (dy < 0 || dy > 2) continue;
                        const int d2 = dx * 3 + dy;
                        #pragma unroll
                        for (int ozl = 0; ozl < 6; ++ozl) {
                            if (ozl & 1) {
                                const int vi = (ozl - 1) / 2 + 1;
                                acc[0][o][p][ozl] = fdot2u(A0[d2], V[vi],
                                    fdot2u(Be0[d2], V[vi + 1], acc[0][o][p][ozl]));
                                acc[1][o][p][ozl] = fdot2u(A1[d2], V[vi],
                                    fdot2u(Be1[d2], V[vi + 1], acc[1][o][p][ozl]));
                            } else {
                                const int si = ozl / 2;
                                acc[0][o][p][ozl] = fdot2u(A0[d2], Sh[si],
                                    fdot2u(Be0[d2], Sh[si + 1], acc[0][o][p][ozl]));
                                acc[1][o][p][ozl] = fdot2u(A1[d2], Sh[si],
                                    fdot2u(Be1[d2], Sh[si + 1], acc[1][o][p][ozl]));
                            }
                        }
                    }
                }
            }
        }
    }
    // 2x2x2 pool in-register + bias; packed float2 write; stats
    const float bb0 = bias[2 * c2], bb1 = bias[2 * c2 + 1];
    float s0 = 0.0f, q0 = 0.0f, s1 = 0.0f, q1 = 0.0f;
    #pragma unroll
    for (int Zp = 0; Zp < 3; ++Zp) {
        float m0 = acc[0][0][0][2 * Zp], m1 = acc[1][0][0][2 * Zp];
        #pragma unroll
        for (int o = 0; o < 2; ++o)
            #pragma unroll
            for (int p = 0; p < 2; ++p) {
                m0 = fmaxf(m0, fmaxf(acc[0][o][p][2 * Zp], acc[0][o][p][2 * Zp + 1]));
                m1 = fmaxf(m1, fmaxf(acc[1][o][p][2 * Zp], acc[1][o][p][2 * Zp + 1]));
            }
        float2 vv; vv.x = m0 + bb0; vv.y = m1 + bb1;
        s0 += vv.x; q0 += vv.x * vv.x; s1 += vv.y; q1 += vv.y * vv.y;
        const int spg = (3 * Xg + Xl) * 81 + Yv * 9 + 3 * ZG + Zp;
        *(float2*)&a1[((size_t)b * 729 + spg) * 16 + 2 * c2] = vv;
    }
    atomicAdd(&s_sum[2 * c2], s0);     atomicAdd(&s_ssq[2 * c2], q0);
    atomicAdd(&s_sum[2 * c2 + 1], s1); atomicAdd(&s_ssq[2 * c2 + 1], q1);
}

__global__ __launch_bounds__(256, 3) void k_conv1(const u32* __restrict__ fields,
        const float* __restrict__ w, const float* __restrict__ bias,
        float* __restrict__ a1, float* __restrict__ stO) {
    __shared__ u32 fldH[48 * 18 * 10];   // 34560 B
    __shared__ u32 wpk[432 * 3];         // 5184 B: per (ic,d2,c2): A0,A1,W2pair
    __shared__ float s_sum[16], s_ssq[16];
    const int bx = blockIdx.x, b = bx / 3, Xg = bx % 3, tid = threadIdx.x;

    for (int i = tid; i < 432; i += 256) {
        const int c2 = i & 7, t = i >> 3, d2 = t % 9, ic = t / 9;
        const int w0 = (2 * c2) * 162 + ic * 27 + d2 * 3;
        const int w1 = w0 + 162;
        wpk[i * 3]     = pkh(w[w0], w[w0 + 1]);
        wpk[i * 3 + 1] = pkh(w[w1], w[w1 + 1]);
        wpk[i * 3 + 2] = pkh(w[w0 + 2], w[w1 + 2]);
    }
    if (tid < 16) { s_sum[tid] = 0.0f; s_ssq[tid] = 0.0f; }
    for (int i = tid; i < 8640; i += 256) {
        const int p = i % 10, t = i / 10;          // t = a*18 + iy
        const int iy = t % 18, a = t / 18;
        const int ix = 6 * Xg - 1 + (a & 7);
        u32 v = 0;
        if (p < 9 && ix >= 0 && ix < 18)
            v = fields[((size_t)(b * 6 + (a >> 3)) * 324 + ix * 18 + iy) * 9 + p];
        fldH[t * 10 + p] = v;
    }
    __syncthreads();

    const int c2 = tid & 7, sp = tid >> 3;
    if (tid < 216) {
        const int Xl = sp / 9, Yv = sp % 9;
        conv1_pass<0>(c2, Xl, Yv, b, Xg, fldH, wpk, s_sum, s_ssq, bias, a1);
        conv1_pass<1>(c2, Xl, Yv, b, Xg, fldH, wpk, s_sum, s_ssq, bias, a1);
        conv1_pass<2>(c2, Xl, Yv, b, Xg, fldH, wpk, s_sum, s_ssq, bias, a1);
    }
    __syncthreads();
    if (tid < 16) { atomicAdd(&stO[tid], s_sum[tid]); atomicAdd(&stO[16 + tid], s_ssq[tid]); }
}

// ---------- K2: bn1+leaky -> conv2 (16->32, pad0) + pool -> [32,3^3] + bn2 stats
// single block per env, 576 threads; a1 read in [spatial][ch] layout.
__global__ __launch_bounds__(576) void k_conv2(const float* __restrict__ a1,
        const float* __restrict__ w, const float* __restrict__ bias,
        const float* __restrict__ bng, const float* __restrict__ bnb,
        const float* __restrict__ stI, float* __restrict__ a2,
        float* __restrict__ stO) {
    __shared__ float xin[16 * 729];   // 46656 B
    __shared__ float ws2[13824];      // 55296 B
    __shared__ float sc[16], sh[16];
    __shared__ float s_sum[32], s_ssq[32];
    const int b = blockIdx.x, tid = threadIdx.x;
    if (tid < 16) {
        const float cnt = 256.0f * 729.0f;
        float m = stI[tid] / cnt;
        float v = stI[16 + tid] / cnt - m * m;
        float s = bng[tid] * rsqrtf(fmaxf(v, 0.0f) + EPS);
        sc[tid] = s; sh[tid] = bnb[tid] - m * s;
    }
    if (tid < 32) { s_sum[tid] = 0.0f; s_ssq[tid] = 0.0f; }
    __syncthreads();
    const float* src = a1 + (size_t)b * 729 * 16;
    for (int i = tid; i < 16 * 729; i += 576) {
        const int spb = i >> 4, c = i & 15;
        xin[c * 729 + spb] = leaky(src[i] * sc[c] + sh[c]);
    }
    for (int i = tid; i < 13824; i += 576) ws2[i] = w[i];
    __syncthreads();
    {
        const int oyi = tid & 1, oxi = (tid >> 1) & 1, rest = tid >> 2;
        const int Y = rest % 3, X = (rest / 3) % 3, c2 = rest / 9;   // c2 0..15
        const int ox = 2 * X + oxi, oy = 2 * Y + oyi;   // 0..5
        const int c0 = 2 * c2, c1 = c0 + 1;
        float acc0[6], acc1[6];
        #pragma unroll
        for (int z = 0; z < 6; ++z) { acc0[z] = 0.0f; acc1[z] = 0.0f; }
        for (int ic = 0; ic < 16; ++ic) {
            #pragma unroll
            for (int dx = 0; dx < 3; ++dx) {
                const int ix = ox + dx;
                #pragma unroll
                for (int dy = 0; dy < 3; ++dy) {
                    const int iy = oy + dy;
                    const float* rp = &xin[ic * 729 + ix * 81 + iy * 9];
                    float row[9];
                    #pragma unroll
                    for (int z = 0; z < 9; ++z) row[z] = rp[z];
                    const int wb0 = (c0 * 16 + ic) * 27 + dx * 9 + dy * 3;
                    const int wb1 = (c1 * 16 + ic) * 27 + dx * 9 + dy * 3;
                    #pragma unroll
                    for (int dz = 0; dz < 3; ++dz) {
                        const float w0 = ws2[wb0 + dz];
                        const float w1v = ws2[wb1 + dz];
                        #pragma unroll
                        for (int z = 0; z < 6; ++z) {
                            acc0[z] += w0 * row[z + dz];
                            acc1[z] += w1v * row[z + dz];
                        }
                    }
                }
            }
        }
        float pl[2][3];
        #pragma unroll
        for (int Z = 0; Z < 3; ++Z) {
            float v0 = fmaxf(acc0[2 * Z], acc0[2 * Z + 1]);
            float v1 = fmaxf(acc1[2 * Z], acc1[2 * Z + 1]);
            v0 = fmaxf(v0, __shfl_xor(v0, 1)); v0 = fmaxf(v0, __shfl_xor(v0, 2));
            v1 = fmaxf(v1, __shfl_xor(v1, 1)); v1 = fmaxf(v1, __shfl_xor(v1, 2));
            pl[0][Z] = v0; pl[1][Z] = v1;
        }
        if ((tid & 3) == 0) {
            #pragma unroll
            for (int hh = 0; hh < 2; ++hh) {
                const int c = c0 + hh;
                const float bb = bias[c];
                float s0 = 0.0f, q0 = 0.0f;
                #pragma unroll
                for (int Z = 0; Z < 3; ++Z) {
                    const float v = pl[hh][Z] + bb;
                    a2[((size_t)b * 32 + c) * 27 + X * 9 + Y * 3 + Z] = v;
                    s0 += v; q0 += v * v;
                }
                atomicAdd(&s_sum[c], s0); atomicAdd(&s_ssq[c], q0);
            }
        }
    }
    __syncthreads();
    if (tid < 32) { atomicAdd(&stO[tid], s_sum[tid]); atomicAdd(&stO[32 + tid], s_ssq[tid]); }
}

// ---------- K3: bn2+leaky -> conv3 (32->64, pad1, 3^3) + pool -> [64] + bn3 stats
__global__ __launch_bounds__(256) void k_conv3(const float* __restrict__ a2,
        const float* __restrict__ w, const float* __restrict__ bias,
        const float* __restrict__ bng, const float* __restrict__ bnb,
        const float* __restrict__ stI, float* __restrict__ a3,
        float* __restrict__ stO) {
    __shared__ float x[864];
    __shared__ float pacc[256 * 8];
    __shared__ float sc[32], sh[32];
    const int b = blockIdx.x, tid = threadIdx.x;
    if (tid < 32) {
        const float cnt = 256.0f * 27.0f;
        float m = stI[tid] / cnt;
        float v = stI[32 + tid] / cnt - m * m;
        float s = bng[tid] * rsqrtf(fmaxf(v, 0.0f) + EPS);
        sc[tid] = s; sh[tid] = bnb[tid] - m * s;
    }
    __syncthreads();
    for (int i = tid; i < 864; i += 256) {
        int c = i / 27;
        x[i] = leaky(a2[(size_t)b * 864 + i] * sc[c] + sh[c]);
    }
    __syncthreads();
    const int c = tid & 63, q = tid >> 6;
    float acc[8];
    #pragma unroll
    for (int p = 0; p < 8; ++p) acc[p] = 0.0f;
    for (int ic = q * 8; ic < q * 8 + 8; ++ic) {
        const float* wr = w + ((size_t)c * 32 + ic) * 27;
        #pragma unroll
        for (int d = 0; d < 27; ++d) {
            const int dx = d / 9, dy = (d / 3) % 3, dz = d % 3;
            const float wv = wr[d];
            #pragma unroll
            for (int p = 0; p < 8; ++p) {
                const int px = p >> 2, py = (p >> 1) & 1, pz = p & 1;
                const int ix = px + dx - 1, iy = py + dy - 1, iz = pz + dz - 1;
                if (ix >= 0 && iy >= 0 && iz >= 0)
                    acc[p] += wv * x[ic * 27 + ix * 9 + iy * 3 + iz];
            }
        }
    }
    #pragma unroll
    for (int p = 0; p < 8; ++p) pacc[tid * 8 + p] = acc[p];
    __syncthreads();
    if (q == 0) {
        float m = -1e30f;
        #pragma unroll
        for (int p = 0; p < 8; ++p) {
            float v = pacc[c * 8 + p] + pacc[(64 + c) * 8 + p]
                    + pacc[(128 + c) * 8 + p] + pacc[(192 + c) * 8 + p];
            m = fmaxf(m, v);
        }
        float v = m + bias[c];
        a3[(size_t)b * 64 + c] = v;
        atomicAdd(&stO[c], v); atomicAdd(&stO[64 + c], v * v);
    }
}

// ---------- K4: bn3+leaky -> dense 64->128 (pre-bn4) + bn4 stats
__global__ __launch_bounds__(128) void k_dense1(const float* __restrict__ a3,
        const float* __restrict__ bng, const float* __restrict__ bnb,
        const float* __restrict__ stI,
        const float* __restrict__ w1, const float* __restrict__ b1,
        float* __restrict__ h1, float* __restrict__ stO) {
    __shared__ float x[64];
    const int b = blockIdx.x, tid = threadIdx.x;
    if (tid < 64) {
        float m = stI[tid] / 256.0f;
        float v = stI[64 + tid] / 256.0f - m * m;
        float s = bng[tid] * rsqrtf(fmaxf(v, 0.0f) + EPS);
        x[tid] = leaky(a3[(size_t)b * 64 + tid] * s + (bnb[tid] - m * s));
    }
    __syncthreads();
    const float* wr = w1 + tid * 64;
    float acc = b1[tid];
    #pragma unroll
    for (int i = 0; i < 64; ++i) acc += x[i] * wr[i];
    h1[(size_t)b * 128 + tid] = acc;
    atomicAdd(&stO[tid], acc); atomicAdd(&stO[128 + tid], acc * acc);
}

// ---------- K5: bn4+leaky -> 128->100 (+leaky) -> 100->20 -> out (f32)
__global__ __launch_bounds__(128) void k_dense2(const float* __restrict__ h1,
        const float* __restrict__ bng, const float* __restrict__ bnb,
        const float* __restrict__ stI,
        const float* __restrict__ w2, const float* __restrict__ bias2,
        const float* __restrict__ w3, const float* __restrict__ bias3,
        float* __restrict__ out) {
    __shared__ float x[128];
    __shared__ float y[100];
    const int b = blockIdx.x, tid = threadIdx.x;
    {
        float m = stI[tid] / 256.0f;
        float v = stI[128 + tid] / 256.0f - m * m;
        float s = bng[tid] * rsqrtf(fmaxf(v, 0.0f) + EPS);
        x[tid] = leaky(h1[(size_t)b * 128 + tid] * s + (bnb[tid] - m * s));
    }
    __syncthreads();
    if (tid < 100) {
        const float* wr = w2 + tid * 128;
        float acc = bias2[tid];
        #pragma unroll
        for (int i = 0; i < 128; ++i) acc += x[i] * wr[i];
        y[tid] = leaky(acc);
    }
    __syncthreads();
    if (tid < 20) {
        const float* wr = w3 + tid * 100;
        float acc = bias3[tid];
        #pragma unroll
        for (int i = 0; i < 100; ++i) acc += y[i] * wr[i];
        out[(size_t)b * 20 + tid] = acc;
    }
}

extern "C" void kernel_launch(void* const* d_in, const int* in_sizes, int n_in,
                              void* d_out, int out_size, void* d_ws, size_t ws_size,
                              hipStream_t stream) {
    (void)in_sizes; (void)n_in; (void)out_size; (void)ws_size;
    const float* pos  = (const float*)d_in[0];
    const float* c1w  = (const float*)d_in[1];
    const float* c1b  = (const float*)d_in[2];
    const float* bn1g = (const float*)d_in[3];
    const float* bn1b = (const float*)d_in[4];
    const float* c2w  = (const float*)d_in[5];
    const float* c2b  = (const float*)d_in[6];
    const float* bn2g = (const float*)d_in[7];
    const float* bn2b = (const float*)d_in[8];
    const float* c3w  = (const float*)d_in[9];
    const float* c3b  = (const float*)d_in[10];
    const float* bn3g = (const float*)d_in[11];
    const float* bn3b = (const float*)d_in[12];
    const float* d1w  = (const float*)d_in[13];
    const float* d1b  = (const float*)d_in[14];
    const float* bn4g = (const float*)d_in[15];
    const float* bn4b = (const float*)d_in[16];
    const float* d2w  = (const float*)d_in[17];
    const float* d2b  = (const float*)d_in[18];
    const float* d3w  = (const float*)d_in[19];
    const float* d3b  = (const float*)d_in[20];
    const int* types  = (const int*)d_in[22];   // d_in[21]=batch_ids implied by layout

    float* ws = (float*)d_ws;
    float* st = ws;                         // 480 f (bn stats)
    float* a3 = ws + 512;                   // 16,384 f
    float* h1 = a3 + 16384;                 // 32,768 f
    float* a2 = h1 + 32768;                 // 221,184 f
    float* a1 = a2 + 221184;                // 2,985,984 f  [b][729][16]
    u32* fields = (u32*)(a1 + 2985984);     // f16 pairs: 4,478,976 u32 (~31 MB total)

    hipMemsetAsync(st, 0, 480 * sizeof(float), stream);
    k_splat <<<BATCH, 512, 0, stream>>>(pos, types, fields);
    k_conv1 <<<3 * BATCH, 256, 0, stream>>>(fields, c1w, c1b, a1, st);
    k_conv2 <<<BATCH, 576, 0, stream>>>(a1, c2w, c2b, bn1g, bn1b, st, a2, st + 32);
    k_conv3 <<<BATCH, 256, 0, stream>>>(a2, c3w, c3b, bn2g, bn2b, st + 32, a3, st + 96);
    k_dense1<<<BATCH, 128, 0, stream>>>(a3, bn3g, bn3b, st + 96, d1w, d1b, h1, st + 224);
    k_dense2<<<BATCH, 128, 0, stream>>>(h1, bn4g, bn4b, st + 224, d2w, d2b, d3w, d3b,
                                        (float*)d_out);
}